// Round 1
// baseline (248.787 us; speedup 1.0000x reference)
//
#include <hip/hip_runtime.h>
#include <math.h>

#define DEV_INLINE __device__ __forceinline__

// Constants computed in double then truncated to float, matching Python float
// semantics when they enter jnp float32 arithmetic.
__device__ const float kLF      = 1.5f;
__device__ const float kLR      = 1.4f;
__device__ const float kCM1     = 550.0f;
__device__ const float kCM2     = 650.0f;
__device__ const float kDT      = 0.01f;
__device__ const float kGRAV    = 9.8f;
__device__ const float kCDRIVE  = (float)(3.45 * 0.919 / (0.34 * 1265.0));
__device__ const float kMASS    = 1265.0f;
__device__ const float kIZ_INV  = (float)(1.0 / 2000.0);

// 1 -> 12 -> 1 ReLU MLP: relu(a*w1 + b1) . w2 + b2
DEV_INLINE float mlp12(float a, const float* __restrict__ w1,
                       const float* __restrict__ b1,
                       const float* __restrict__ w2, float b2) {
    float acc = b2;
#pragma unroll
    for (int j = 0; j < 12; ++j) {
        float h = fmaxf(fmaf(a, w1[j], b1[j]), 0.0f);
        acc = fmaf(h, w2[j], acc);
    }
    return acc;
}

__global__ __launch_bounds__(256) void dyn_kernel(
    const float4* __restrict__ x4,
    const float* __restrict__ fy_w1, const float* __restrict__ fy_b1,
    const float* __restrict__ fy_w2, const float* __restrict__ fy_b2,
    const float* __restrict__ ry_w1, const float* __restrict__ ry_b1,
    const float* __restrict__ ry_w2, const float* __restrict__ ry_b2,
    const float* __restrict__ rx_w, const float* __restrict__ rx_b,
    float4* __restrict__ out4, int nrows) {
    // ---- uniform weights (wave-uniform addresses -> scalar loads) ----
    float fw1[12], fb1[12], fw2[12];
    float rw1[12], rb1[12], rw2[12];
#pragma unroll
    for (int j = 0; j < 12; ++j) {
        fw1[j] = fy_w1[j]; fb1[j] = fy_b1[j]; fw2[j] = fy_w2[j];
        rw1[j] = ry_w1[j]; rb1[j] = ry_b1[j]; rw2[j] = ry_w2[j];
    }
    const float fb2 = fy_b2[0];
    const float rb2 = ry_b2[0];
    const float rxw = rx_w[0];
    const float rxb = rx_b[0];

    const int t = blockIdx.x * blockDim.x + threadIdx.x;
    const long long base = (long long)t * 4;  // first row of this thread
    if (base >= nrows) return;

    // ---- load 4 rows, 2 x float4 each ----
    float4 lo[4], hi[4];
#pragma unroll
    for (int r = 0; r < 4; ++r) {
        lo[r] = x4[(base + r) * 2 + 0];  // x0..x3
        hi[r] = x4[(base + r) * 2 + 1];  // x4..x7
    }

    float res[12];

#pragma unroll
    for (int r = 0; r < 4; ++r) {
        const float pwm   = lo[r].x;
        const float theta = lo[r].z;
        const float x3    = lo[r].w;  // vx base
        const float x4v   = hi[r].x;  // vy base
        const float x5    = hi[r].y;  // w base
        const float pitch = hi[r].w;

        const float st = __sinf(theta);
        const float ct = __cosf(theta);
        const float sp = __sinf(pitch);
        const float a_pred = (pwm > 0.0f ? kCM1 : kCM2) * pwm * kCDRIVE;

        float o0 = 0.0f, o1 = 0.0f, o2 = 0.0f;
#pragma unroll
        for (int it = 0; it < 2; ++it) {
            const float vx = x3 + o0;
            const float vy = x4v + o1;
            const float w  = x5 + o2;

            const float af = theta - atan2f(fmaf(w, kLF, vy), vx);
            const float ar = atan2f(fmaf(w, kLR, -vy), vx);

            // where(a > 0, f(a), -f(-a)) == s * f(s*a) with s = (a>0 ? 1 : -1)
            const float sf  = af > 0.0f ? 1.0f : -1.0f;
            const float Ffy = sf * mlp12(sf * af, fw1, fb1, fw2, fb2);
            const float sr  = ar > 0.0f ? 1.0f : -1.0f;
            const float Fry = sr * mlp12(sr * ar, rw1, rb1, rw2, rb2);

            const float Frx = a_pred + rxw * vx * vx + rxb;

            const float vx_dot = Frx - Ffy * st + vy * w - kGRAV * sp;
            const float vy_dot = Fry + Ffy * ct - vx * w;
            const float w_dot  = kMASS * (Ffy * kLF * ct - Fry * kLR) * kIZ_INV;

            o0 = fmaf(kDT, vx_dot, o0);
            o1 = fmaf(kDT, vy_dot, o1);
            o2 = fmaf(kDT, w_dot,  o2);
        }
        res[r * 3 + 0] = o0;
        res[r * 3 + 1] = o1;
        res[r * 3 + 2] = o2;
    }

    // ---- 4 rows x 3 floats = 3 contiguous float4 stores ----
#pragma unroll
    for (int k = 0; k < 3; ++k) {
        out4[(long long)t * 3 + k] =
            make_float4(res[k * 4 + 0], res[k * 4 + 1], res[k * 4 + 2], res[k * 4 + 3]);
    }
}

extern "C" void kernel_launch(void* const* d_in, const int* in_sizes, int n_in,
                              void* d_out, int out_size, void* d_ws, size_t ws_size,
                              hipStream_t stream) {
    const float4* x4   = (const float4*)d_in[0];
    const float* fy_w1 = (const float*)d_in[1];
    const float* fy_b1 = (const float*)d_in[2];
    const float* fy_w2 = (const float*)d_in[3];
    const float* fy_b2 = (const float*)d_in[4];
    const float* ry_w1 = (const float*)d_in[5];
    const float* ry_b1 = (const float*)d_in[6];
    const float* ry_w2 = (const float*)d_in[7];
    const float* ry_b2 = (const float*)d_in[8];
    const float* rx_w  = (const float*)d_in[9];
    const float* rx_b  = (const float*)d_in[10];

    const int nrows = in_sizes[0] / 8;
    const int threads = 256;
    const int rows_per_block = threads * 4;
    const int blocks = (nrows + rows_per_block - 1) / rows_per_block;

    dyn_kernel<<<blocks, threads, 0, stream>>>(
        x4, fy_w1, fy_b1, fy_w2, fy_b2, ry_w1, ry_b1, ry_w2, ry_b2, rx_w, rx_b,
        (float4*)d_out, nrows);
}

// Round 2
// 218.499 us; speedup vs baseline: 1.1386x; 1.1386x over previous
//
#include <hip/hip_runtime.h>
#include <math.h>

#define DEV_INLINE __device__ __forceinline__

// Branch-free fast atan2. Max error ~1e-5 rad; output sensitivity to alpha is
// ~0.07 (2 iters x DT x MLP slope x chassis gains), so contributes ~1e-6 abs
// error vs 1.4e-2 threshold. atan2(0,0) -> NaN is measure-zero on this input.
DEV_INLINE float fast_atan2f(float y, float x) {
    const float kPI  = 3.14159265358979323846f;
    const float kPI2 = 1.57079632679489661923f;
    float ax = fabsf(x), ay = fabsf(y);
    float mx = fmaxf(ax, ay);
    float mn = fminf(ax, ay);
    float a  = mn * __builtin_amdgcn_rcpf(mx);
    float s  = a * a;
    float p  = -0.01172120f;
    p = fmaf(p, s,  0.05265332f);
    p = fmaf(p, s, -0.11643287f);
    p = fmaf(p, s,  0.19354346f);
    p = fmaf(p, s, -0.33262347f);
    p = fmaf(p, s,  0.99997726f);
    float r = a * p;                       // atan(mn/mx) in [0, pi/4]
    r = (ay > ax)   ? (kPI2 - r) : r;      // reflect across pi/4
    r = (x < 0.0f)  ? (kPI  - r) : r;      // reflect across pi/2
    return copysignf(r, y);
}

// 1 -> 12 -> 1 ReLU MLP: relu(a*w1 + b1) . w2 + b2
DEV_INLINE float mlp12(float a, const float* __restrict__ w1,
                       const float* __restrict__ b1,
                       const float* __restrict__ w2, float b2) {
    float acc = b2;
#pragma unroll
    for (int j = 0; j < 12; ++j) {
        float h = fmaxf(fmaf(a, w1[j], b1[j]), 0.0f);
        acc = fmaf(h, w2[j], acc);
    }
    return acc;
}

__global__ __launch_bounds__(256) void dyn_kernel(
    const float4* __restrict__ x4,
    const float* __restrict__ fy_w1, const float* __restrict__ fy_b1,
    const float* __restrict__ fy_w2, const float* __restrict__ fy_b2,
    const float* __restrict__ ry_w1, const float* __restrict__ ry_b1,
    const float* __restrict__ ry_w2, const float* __restrict__ ry_b2,
    const float* __restrict__ rx_w, const float* __restrict__ rx_b,
    float* __restrict__ out, int nrows) {
    const float kLF     = 1.5f;
    const float kLR     = 1.4f;
    const float kCM1    = 550.0f;
    const float kCM2    = 650.0f;
    const float kDT     = 0.01f;
    const float kGRAV   = 9.8f;
    const float kCDRIVE = (float)(3.45 * 0.919 / (0.34 * 1265.0));
    const float kWF     = (float)(1265.0 * 1.5 / 2000.0);  // MASS*LF/IZ
    const float kWR     = (float)(1265.0 * 1.4 / 2000.0);  // MASS*LR/IZ

    __shared__ float sout[768];  // 256 rows x 3 floats, block-level transpose

    // ---- uniform weights (uniform addresses -> scalar loads) ----
    float fw1[12], fb1[12], fw2[12];
    float rw1[12], rb1[12], rw2[12];
#pragma unroll
    for (int j = 0; j < 12; ++j) {
        fw1[j] = fy_w1[j]; fb1[j] = fy_b1[j]; fw2[j] = fy_w2[j];
        rw1[j] = ry_w1[j]; rb1[j] = ry_b1[j]; rw2[j] = ry_w2[j];
    }
    const float fb2 = fy_b2[0];
    const float rb2 = ry_b2[0];
    const float rxw = rx_w[0];
    const float rxb = rx_b[0];

    const int tid = threadIdx.x;
    const long long t = (long long)blockIdx.x * 256 + tid;

    float o0 = 0.0f, o1 = 0.0f, o2 = 0.0f;
    if (t < nrows) {
        // two float4 loads, lane stride 32B: every 32B sector fully consumed
        const float4 lo = x4[2 * t];      // pwm, x1, theta, vx0
        const float4 hi = x4[2 * t + 1];  // vy0, w0, x6, pitch

        const float pwm   = lo.x;
        const float theta = lo.z;
        const float x3    = lo.w;
        const float x4v   = hi.x;
        const float x5    = hi.y;
        const float pitch = hi.w;

        const float st = __sinf(theta);
        const float ct = __cosf(theta);
        const float sp = __sinf(pitch);
        const float a_pred = (pwm > 0.0f ? kCM1 : kCM2) * pwm * kCDRIVE;

#pragma unroll
        for (int it = 0; it < 2; ++it) {
            const float vx = x3 + o0;
            const float vy = x4v + o1;
            const float w  = x5 + o2;

            const float af = theta - fast_atan2f(fmaf(w, kLF, vy), vx);
            const float ar = fast_atan2f(fmaf(w, kLR, -vy), vx);

            // where(a > 0, f(a), -f(-a)) == s * f(s*a), s = sign
            const float sf  = af > 0.0f ? 1.0f : -1.0f;
            const float Ffy = sf * mlp12(sf * af, fw1, fb1, fw2, fb2);
            const float sr  = ar > 0.0f ? 1.0f : -1.0f;
            const float Fry = sr * mlp12(sr * ar, rw1, rb1, rw2, rb2);

            const float Frx = fmaf(rxw * vx, vx, a_pred + rxb);

            const float vx_dot = Frx - Ffy * st + vy * w - kGRAV * sp;
            const float vy_dot = Fry + Ffy * ct - vx * w;
            const float w_dot  = kWF * Ffy * ct - kWR * Fry;

            o0 = fmaf(kDT, vx_dot, o0);
            o1 = fmaf(kDT, vy_dot, o1);
            o2 = fmaf(kDT, w_dot,  o2);
        }
    }

    // ---- LDS transpose: write stride-3 (2-way bank alias = free), read
    // stride-1, then fully lane-contiguous dword stores ----
    sout[tid * 3 + 0] = o0;
    sout[tid * 3 + 1] = o1;
    sout[tid * 3 + 2] = o2;
    __syncthreads();

    const long long gbase = (long long)blockIdx.x * 768;
    const long long gmax  = (long long)nrows * 3;
#pragma unroll
    for (int j = 0; j < 3; ++j) {
        const long long gi = gbase + j * 256 + tid;
        if (gi < gmax) out[gi] = sout[j * 256 + tid];
    }
}

extern "C" void kernel_launch(void* const* d_in, const int* in_sizes, int n_in,
                              void* d_out, int out_size, void* d_ws, size_t ws_size,
                              hipStream_t stream) {
    const float4* x4   = (const float4*)d_in[0];
    const float* fy_w1 = (const float*)d_in[1];
    const float* fy_b1 = (const float*)d_in[2];
    const float* fy_w2 = (const float*)d_in[3];
    const float* fy_b2 = (const float*)d_in[4];
    const float* ry_w1 = (const float*)d_in[5];
    const float* ry_b1 = (const float*)d_in[6];
    const float* ry_w2 = (const float*)d_in[7];
    const float* ry_b2 = (const float*)d_in[8];
    const float* rx_w  = (const float*)d_in[9];
    const float* rx_b  = (const float*)d_in[10];

    const int nrows = in_sizes[0] / 8;
    const int threads = 256;
    const int blocks = (nrows + threads - 1) / threads;

    dyn_kernel<<<blocks, threads, 0, stream>>>(
        x4, fy_w1, fy_b1, fy_w2, fy_b2, ry_w1, ry_b1, ry_w2, ry_b2, rx_w, rx_b,
        (float*)d_out, nrows);
}